// Round 2
// baseline (1835.182 us; speedup 1.0000x reference)
//
#include <hip/hip_runtime.h>
#include <hip/hip_bf16.h>
#include <hip/hip_fp16.h>

namespace {
constexpr int kN = 100000;   // nodes
constexpr int kE = 3200000;  // edges
constexpr int kD = 256;      // node_dim
constexpr int kH = 64;       // hidden = latent = 64
constexpr int kG = 128;      // graphs

constexpr size_t kAlign = 512;
constexpr size_t align_up(size_t v) { return (v + kAlign - 1) & ~(kAlign - 1); }

constexpr size_t SZ_N_I   = align_up((size_t)kN * 4);
// ---- zeroed region ----
constexpr size_t OFF_CNTD = 0;                           // int[N]  in-degree (dst)
constexpr size_t OFF_CURD = OFF_CNTD + SZ_N_I;           // int[N]  dst fill cursors
constexpr size_t OFF_CNTS = OFF_CURD + SZ_N_I;           // int[N]  out-degree (src)
constexpr size_t OFF_CURS = OFF_CNTS + SZ_N_I;           // int[N]  src fill cursors
constexpr size_t OFF_GCNT = OFF_CURS + SZ_N_I;           // int[G]
constexpr size_t OFF_QRAW = OFF_GCNT + kAlign;           // f32[G*H]
constexpr size_t ZERO_BYTES = OFF_QRAW + align_up((size_t)kG * kH * 4);
// ---- rest ----
constexpr size_t OFF_DINV  = ZERO_BYTES;                 // f32[N]
constexpr size_t OFF_ROWPD = OFF_DINV + SZ_N_I;          // int[N]
constexpr size_t OFF_ROWPS = OFF_ROWPD + SZ_N_I;         // int[N]
constexpr size_t OFF_BSUM  = OFF_ROWPS + SZ_N_I;         // int[512]
constexpr size_t OFF_BOFF  = OFF_BSUM + 4096;            // int[512]
constexpr size_t OFF_RECD  = OFF_BOFF + 4096;            // int2[E]  (src, w_f32) by dst
constexpr size_t OFF_RECS  = OFF_RECD + align_up((size_t)kE * 8);  // u32[E] (w_bf16<<16|g) by src
constexpr size_t OFF_HL    = OFF_RECS + align_up((size_t)kE * 4);  // fp16[N*64] x@W1
constexpr size_t OFF_H2    = OFF_HL + align_up((size_t)kN * kH * 2); // fp16[N*64] relu(conv1)
} // namespace

// ---------- degree histograms over dst and src ----------
__global__ void k_hist(const int* __restrict__ src, const int* __restrict__ dst,
                       int* __restrict__ cnt_d, int* __restrict__ cnt_s) {
    int e = blockIdx.x * blockDim.x + threadIdx.x;
    if (e < kE) {
        atomicAdd(&cnt_d[dst[e]], 1);
        atomicAdd(&cnt_s[src[e]], 1);
    }
}

// ---------- per-graph node counts (batch sorted; LDS-aggregated) ----------
__global__ void k_gcnt(const int* __restrict__ batch, int* __restrict__ gcnt) {
    __shared__ int h[kG];
    int t = threadIdx.x;
    if (t < kG) h[t] = 0;
    __syncthreads();
    for (int i = blockIdx.x * blockDim.x + t; i < kN; i += gridDim.x * blockDim.x)
        atomicAdd(&h[batch[i]], 1);
    __syncthreads();
    if (t < kG && h[t]) atomicAdd(&gcnt[t], h[t]);
}

// ---------- dinv = rsqrt(indeg + 1) ----------
__global__ void k_dinv(const int* __restrict__ cnt, float* __restrict__ dinv) {
    int i = blockIdx.x * blockDim.x + threadIdx.x;
    if (i < kN) dinv[i] = rsqrtf((float)(cnt[i] + 1));
}

// ---------- exclusive scan of counts -> row_ptr (3 kernels) ----------
__global__ void k_scan1(const int* __restrict__ cnt, int* __restrict__ rowp,
                        int* __restrict__ bsum) {
    __shared__ int s[256];
    int t = threadIdx.x;
    int i = blockIdx.x * 256 + t;
    int v = (i < kN) ? cnt[i] : 0;
    s[t] = v;
    __syncthreads();
    for (int off = 1; off < 256; off <<= 1) {
        int add = (t >= off) ? s[t - off] : 0;
        __syncthreads();
        s[t] += add;
        __syncthreads();
    }
    if (i < kN) rowp[i] = s[t] - v;
    if (t == 255) bsum[blockIdx.x] = s[255];
}

__global__ void k_scan2(const int* __restrict__ bsum, int* __restrict__ boff, int nb) {
    __shared__ int s[512];
    int t = threadIdx.x;
    int v = (t < nb) ? bsum[t] : 0;
    s[t] = v;
    __syncthreads();
    for (int off = 1; off < 512; off <<= 1) {
        int add = (t >= off) ? s[t - off] : 0;
        __syncthreads();
        s[t] += add;
        __syncthreads();
    }
    if (t < nb) boff[t] = s[t] - v;
}

__global__ void k_scan3(int* __restrict__ rowp, const int* __restrict__ boff) {
    int i = blockIdx.x * 256 + threadIdx.x;
    if (i < kN) rowp[i] += boff[blockIdx.x];
}

// ---------- CSR fill: both CSRs in one edge pass ----------
__global__ void k_fill(const int* __restrict__ src, const int* __restrict__ dst,
                       const int* __restrict__ batch, const float* __restrict__ dinv,
                       const int* __restrict__ rowp_d, int* __restrict__ cur_d,
                       const int* __restrict__ rowp_s, int* __restrict__ cur_s,
                       int2* __restrict__ rec_d, unsigned* __restrict__ rec_s) {
    int e = blockIdx.x * blockDim.x + threadIdx.x;
    if (e >= kE) return;
    int s = src[e], d = dst[e];
    float w = dinv[s] * dinv[d];
    int pd = rowp_d[d] + atomicAdd(&cur_d[d], 1);
    rec_d[pd] = make_int2(s, __float_as_int(w));
    int ps = rowp_s[s] + atomicAdd(&cur_s[s], 1);
    unsigned wb = (__float_as_uint(w) + 0x8000u) & 0xffff0000u;   // round-to-nearest bf16
    rec_s[ps] = wb | (unsigned)batch[d];
}

// ---------- GEMM1: hl[N][64] = x[N][256] @ W1[256][64], fp16 store ----------
__global__ __launch_bounds__(256) void k_gemm1(const float* __restrict__ x,
                                               const float* __restrict__ W1,
                                               __half* __restrict__ hl) {
    constexpr int TM = 64;
    constexpr int KC = 32;
    __shared__ float xs[TM][36];
    __shared__ float ws[KC][kH];
    int t = threadIdx.x;
    int tx = t & 15;
    int ty = t >> 4;
    int nb = blockIdx.x * TM;
    float acc[4][4] = {};
    for (int k0 = 0; k0 < kD; k0 += KC) {
        #pragma unroll
        for (int j = 0; j < 2; ++j) {
            int id = t * 2 + j;
            int row = id >> 3;
            int c4 = (id & 7) * 4;
            int node = nb + row;
            if (node >= kN) node = kN - 1;
            float4 v = *(const float4*)(x + (size_t)node * kD + k0 + c4);
            *(float4*)&xs[row][c4] = v;
        }
        #pragma unroll
        for (int j = 0; j < 2; ++j) {
            int id = t * 2 + j;
            int row = id >> 4;
            int c4 = (id & 15) * 4;
            float4 v = *(const float4*)(W1 + (size_t)(k0 + row) * kH + c4);
            *(float4*)&ws[row][c4] = v;
        }
        __syncthreads();
        #pragma unroll
        for (int kk = 0; kk < KC; ++kk) {
            float a0 = xs[ty * 4 + 0][kk];
            float a1 = xs[ty * 4 + 1][kk];
            float a2 = xs[ty * 4 + 2][kk];
            float a3 = xs[ty * 4 + 3][kk];
            float4 b = *(const float4*)&ws[kk][tx * 4];
            acc[0][0] = fmaf(a0, b.x, acc[0][0]); acc[0][1] = fmaf(a0, b.y, acc[0][1]);
            acc[0][2] = fmaf(a0, b.z, acc[0][2]); acc[0][3] = fmaf(a0, b.w, acc[0][3]);
            acc[1][0] = fmaf(a1, b.x, acc[1][0]); acc[1][1] = fmaf(a1, b.y, acc[1][1]);
            acc[1][2] = fmaf(a1, b.z, acc[1][2]); acc[1][3] = fmaf(a1, b.w, acc[1][3]);
            acc[2][0] = fmaf(a2, b.x, acc[2][0]); acc[2][1] = fmaf(a2, b.y, acc[2][1]);
            acc[2][2] = fmaf(a2, b.z, acc[2][2]); acc[2][3] = fmaf(a2, b.w, acc[2][3]);
            acc[3][0] = fmaf(a3, b.x, acc[3][0]); acc[3][1] = fmaf(a3, b.y, acc[3][1]);
            acc[3][2] = fmaf(a3, b.z, acc[3][2]); acc[3][3] = fmaf(a3, b.w, acc[3][3]);
        }
        __syncthreads();
    }
    #pragma unroll
    for (int i = 0; i < 4; ++i) {
        int node = nb + ty * 4 + i;
        if (node < kN) {
            __half2 p0 = __floats2half2_rn(acc[i][0], acc[i][1]);
            __half2 p1 = __floats2half2_rn(acc[i][2], acc[i][3]);
            __half2* dst2 = (__half2*)(hl + (size_t)node * kH + tx * 4);
            dst2[0] = p0;
            dst2[1] = p1;
        }
    }
}

// ---------- conv1: h = relu(Ahat @ hl + b1), one wave per node, 2 edges/instr ----------
__global__ __launch_bounds__(256) void k_conv1(const int2* __restrict__ rec,
                                               const int* __restrict__ rowp,
                                               const int* __restrict__ cnt,
                                               const float* __restrict__ dinv,
                                               const __half* __restrict__ hl,
                                               const float* __restrict__ b1,
                                               __half* __restrict__ h) {
    int tid = threadIdx.x;
    int lane = tid & 63;
    int node = blockIdx.x * 4 + (tid >> 6);
    if (node >= kN) return;
    int hf = lane >> 5;      // 0: even edges, 1: odd edges
    int fp = lane & 31;      // feature pair: features 2*fp, 2*fp+1
    int base = rowp[node], len = cnt[node];
    float ax = 0.f, ay = 0.f;
    for (int c0 = 0; c0 < len; c0 += 64) {
        int m = len - c0; if (m > 64) m = 64;
        int2 r = make_int2(0, 0);                  // w=0 for pad lanes
        if (lane < m) r = rec[base + c0 + lane];
        int kp = (m + 1) >> 1;
        #pragma unroll 4
        for (int k = 0; k < kp; ++k) {
            int idx = 2 * k + hf;                  // per-half-wave edge index
            int s   = __shfl(r.x, idx, 64);
            float w = __int_as_float(__shfl(r.y, idx, 64));
            __half2 v = *(const __half2*)(hl + ((size_t)s << 6) + 2 * fp);
            float2 vf = __half22float2(v);
            ax = fmaf(w, vf.x, ax);
            ay = fmaf(w, vf.y, ay);
        }
    }
    // combine even/odd partials across the half-wave split
    ax += __shfl_xor(ax, 32, 64);
    ay += __shfl_xor(ay, 32, 64);
    float di = dinv[node], d2 = di * di;
    __half2 sv = *(const __half2*)(hl + ((size_t)node << 6) + 2 * fp);
    float2 svf = __half22float2(sv);
    ax = fmaf(d2, svf.x, ax);
    ay = fmaf(d2, svf.y, ay);
    float2 bb = *(const float2*)(b1 + 2 * fp);
    ax = fmaxf(ax + bb.x, 0.f);
    ay = fmaxf(ay + bb.y, 0.f);
    if (hf == 0)
        *(__half2*)(h + ((size_t)node << 6) + 2 * fp) = __floats2half2_rn(ax, ay);
}

// ---------- pool as scatter-by-src into per-block LDS graph accumulators ----------
__global__ __launch_bounds__(256) void k_pool2(const unsigned* __restrict__ rec,
                                               const int* __restrict__ rowp,
                                               const int* __restrict__ cnt,
                                               const float* __restrict__ dinv,
                                               const __half* __restrict__ h,
                                               const int* __restrict__ batch,
                                               float* __restrict__ q_raw) {
    __shared__ float q[kG * kH];   // 32 KB
    int tid = threadIdx.x;
    for (int i = tid; i < kG * kH; i += 256) q[i] = 0.f;
    __syncthreads();
    int lane = tid & 63;
    int wid = blockIdx.x * 4 + (tid >> 6);
    int nwaves = gridDim.x * 4;
    for (int node = wid; node < kN; node += nwaves) {
        float hj = __half2float(h[((size_t)node << 6) + lane]);
        float di = dinv[node];
        int gs = batch[node];
        atomicAdd(&q[(gs << 6) + lane], di * di * hj);   // self-loop contribution
        int base = rowp[node], len = cnt[node];
        for (int c0 = 0; c0 < len; c0 += 64) {
            int m = len - c0; if (m > 64) m = 64;
            unsigned u = 0;
            if (lane < m) u = rec[base + c0 + lane];
            #pragma unroll 4
            for (int k = 0; k < m; ++k) {
                unsigned uu = (unsigned)__shfl((int)u, k, 64);
                float w = __uint_as_float(uu & 0xffff0000u);
                int g = uu & 0xffff;
                atomicAdd(&q[(g << 6) + lane], w * hj);
            }
        }
    }
    __syncthreads();
    for (int i = tid; i < kG * kH; i += 256) {
        float v = q[i];
        if (v != 0.f) atomicAdd(&q_raw[i], v);
    }
}

// ---------- head: z_pool = (q_raw/cnt)@W2 + b2 ; decoder MLP ----------
__global__ __launch_bounds__(64) void k_head(const float* __restrict__ q_raw,
                                             const int* __restrict__ gcnt,
                                             const float* __restrict__ W2,
                                             const float* __restrict__ b2,
                                             const float* __restrict__ Wd1,
                                             const float* __restrict__ bd1,
                                             const float* __restrict__ Wd2,
                                             const float* __restrict__ bd2,
                                             float* __restrict__ out) {
    __shared__ float zm[kH], zp[kH], tt[kH];
    int g = blockIdx.x, c = threadIdx.x;
    int cg = gcnt[g];
    float inv = (cg > 0) ? 1.f / (float)cg : 0.f;
    zm[c] = q_raw[(size_t)g * kH + c] * inv;
    __syncthreads();
    float a = b2[c];
    #pragma unroll 8
    for (int k = 0; k < kH; ++k) a = fmaf(zm[k], W2[k * kH + c], a);
    if (cg == 0) a = 0.f;
    out[(size_t)kG * kD + (size_t)g * kH + c] = a;   // z_pool
    zp[c] = a;
    __syncthreads();
    float t = bd1[c];
    #pragma unroll 8
    for (int k = 0; k < kH; ++k) t = fmaf(zp[k], Wd1[k * 64 + c], t);
    tt[c] = fmaxf(t, 0.f);
    __syncthreads();
    #pragma unroll
    for (int j4 = 0; j4 < 4; ++j4) {
        int col = c + j4 * 64;
        float v = bd2[col];
        #pragma unroll 8
        for (int k = 0; k < 64; ++k) v = fmaf(tt[k], Wd2[k * kD + col], v);
        out[(size_t)g * kD + col] = v;               // x_hat
    }
}

extern "C" void kernel_launch(void* const* d_in, const int* in_sizes, int n_in,
                              void* d_out, int out_size, void* d_ws, size_t ws_size,
                              hipStream_t stream) {
    const float* x    = (const float*)d_in[0];
    const int*   ei   = (const int*)d_in[1];
    const int*   src  = ei;
    const int*   dst  = ei + kE;
    const int*   batch= (const int*)d_in[2];
    const float* W1   = (const float*)d_in[3];
    const float* b1   = (const float*)d_in[4];
    const float* W2   = (const float*)d_in[5];
    const float* b2   = (const float*)d_in[6];
    const float* Wd1  = (const float*)d_in[7];
    const float* bd1  = (const float*)d_in[8];
    const float* Wd2  = (const float*)d_in[9];
    const float* bd2  = (const float*)d_in[10];
    float* out = (float*)d_out;

    char* ws = (char*)d_ws;
    int*     cnt_d  = (int*)(ws + OFF_CNTD);
    int*     cur_d  = (int*)(ws + OFF_CURD);
    int*     cnt_s  = (int*)(ws + OFF_CNTS);
    int*     cur_s  = (int*)(ws + OFF_CURS);
    int*     gcnt   = (int*)(ws + OFF_GCNT);
    float*   q_raw  = (float*)(ws + OFF_QRAW);
    float*   dinv   = (float*)(ws + OFF_DINV);
    int*     rowp_d = (int*)(ws + OFF_ROWPD);
    int*     rowp_s = (int*)(ws + OFF_ROWPS);
    int*     bsum   = (int*)(ws + OFF_BSUM);
    int*     boff   = (int*)(ws + OFF_BOFF);
    int2*    rec_d  = (int2*)(ws + OFF_RECD);
    unsigned* rec_s = (unsigned*)(ws + OFF_RECS);
    __half*  hl     = (__half*)(ws + OFF_HL);
    __half*  h      = (__half*)(ws + OFF_H2);

    hipMemsetAsync(d_ws, 0, ZERO_BYTES, stream);

    const int nScanBlocks = (kN + 255) / 256;  // 391

    k_hist<<<(kE + 255) / 256, 256, 0, stream>>>(src, dst, cnt_d, cnt_s);
    k_gcnt<<<128, 256, 0, stream>>>(batch, gcnt);
    k_dinv<<<nScanBlocks, 256, 0, stream>>>(cnt_d, dinv);

    k_scan1<<<nScanBlocks, 256, 0, stream>>>(cnt_d, rowp_d, bsum);
    k_scan2<<<1, 512, 0, stream>>>(bsum, boff, nScanBlocks);
    k_scan3<<<nScanBlocks, 256, 0, stream>>>(rowp_d, boff);

    k_scan1<<<nScanBlocks, 256, 0, stream>>>(cnt_s, rowp_s, bsum);
    k_scan2<<<1, 512, 0, stream>>>(bsum, boff, nScanBlocks);
    k_scan3<<<nScanBlocks, 256, 0, stream>>>(rowp_s, boff);

    k_fill<<<(kE + 255) / 256, 256, 0, stream>>>(src, dst, batch, dinv,
                                                 rowp_d, cur_d, rowp_s, cur_s,
                                                 rec_d, rec_s);

    k_gemm1<<<(kN + 63) / 64, 256, 0, stream>>>(x, W1, hl);

    k_conv1<<<(kN + 3) / 4, 256, 0, stream>>>(rec_d, rowp_d, cnt_d, dinv, hl, b1, h);

    k_pool2<<<256, 256, 0, stream>>>(rec_s, rowp_s, cnt_s, dinv, h, batch, q_raw);

    k_head<<<kG, 64, 0, stream>>>(q_raw, gcnt, W2, b2, Wd1, bd1, Wd2, bd2, out);
}

// Round 3
// 562.035 us; speedup vs baseline: 3.2652x; 3.2652x over previous
//
#include <hip/hip_runtime.h>
#include <hip/hip_bf16.h>
#include <hip/hip_fp16.h>

namespace {
constexpr int kN = 100000;   // nodes
constexpr int kE = 3200000;  // edges
constexpr int kD = 256;      // node_dim
constexpr int kH = 64;       // hidden = latent = 64
constexpr int kG = 128;      // graphs

constexpr size_t kAlign = 512;
constexpr size_t align_up(size_t v) { return (v + kAlign - 1) & ~(kAlign - 1); }

constexpr size_t SZ_N_I   = align_up((size_t)kN * 4);
// ---- zeroed region ----
constexpr size_t OFF_CNTD = 0;                           // int[N]  in-degree (dst)
constexpr size_t OFF_CURD = OFF_CNTD + SZ_N_I;           // int[N]  dst fill cursors
constexpr size_t OFF_GCNT = OFF_CURD + SZ_N_I;           // int[G]
constexpr size_t OFF_QRAW = OFF_GCNT + kAlign;           // f32[G*H]
constexpr size_t ZERO_BYTES = OFF_QRAW + align_up((size_t)kG * kH * 4);
// ---- rest ----
constexpr size_t OFF_DINV  = ZERO_BYTES;                 // f32[N]
constexpr size_t OFF_ROWPD = OFF_DINV + SZ_N_I;          // int[N]
constexpr size_t OFF_BSUM  = OFF_ROWPD + SZ_N_I;         // int[512]
constexpr size_t OFF_BOFF  = OFF_BSUM + 4096;            // int[512]
constexpr size_t OFF_RECD  = OFF_BOFF + 4096;            // int2[E] (src, w_f32) by dst
constexpr size_t OFF_HL    = OFF_RECD + align_up((size_t)kE * 8);    // fp16[N*64] x@W1
constexpr size_t OFF_H2    = OFF_HL + align_up((size_t)kN * kH * 2); // fp16[N*64] relu(conv1)
} // namespace

// fused multiply-add of 8 fp16 features (as uint4) into 8 f32 accumulators
__device__ __forceinline__ void fma8(float (&acc)[8], float w, uint4 u) {
    const __half2* hp = (const __half2*)&u;
    #pragma unroll
    for (int j = 0; j < 4; ++j) {
        float2 f = __half22float2(hp[j]);
        acc[2 * j]     = fmaf(w, f.x, acc[2 * j]);
        acc[2 * j + 1] = fmaf(w, f.y, acc[2 * j + 1]);
    }
}

// ---------- degree histogram over dst ----------
__global__ void k_hist(const int* __restrict__ dst, int* __restrict__ cnt_d) {
    int e = blockIdx.x * blockDim.x + threadIdx.x;
    if (e < kE) atomicAdd(&cnt_d[dst[e]], 1);
}

// ---------- per-graph node counts (batch sorted; LDS-aggregated) ----------
__global__ void k_gcnt(const int* __restrict__ batch, int* __restrict__ gcnt) {
    __shared__ int h[kG];
    int t = threadIdx.x;
    if (t < kG) h[t] = 0;
    __syncthreads();
    for (int i = blockIdx.x * blockDim.x + t; i < kN; i += gridDim.x * blockDim.x)
        atomicAdd(&h[batch[i]], 1);
    __syncthreads();
    if (t < kG && h[t]) atomicAdd(&gcnt[t], h[t]);
}

// ---------- dinv = rsqrt(indeg + 1) ----------
__global__ void k_dinv(const int* __restrict__ cnt, float* __restrict__ dinv) {
    int i = blockIdx.x * blockDim.x + threadIdx.x;
    if (i < kN) dinv[i] = rsqrtf((float)(cnt[i] + 1));
}

// ---------- exclusive scan of counts -> row_ptr (3 kernels) ----------
__global__ void k_scan1(const int* __restrict__ cnt, int* __restrict__ rowp,
                        int* __restrict__ bsum) {
    __shared__ int s[256];
    int t = threadIdx.x;
    int i = blockIdx.x * 256 + t;
    int v = (i < kN) ? cnt[i] : 0;
    s[t] = v;
    __syncthreads();
    for (int off = 1; off < 256; off <<= 1) {
        int add = (t >= off) ? s[t - off] : 0;
        __syncthreads();
        s[t] += add;
        __syncthreads();
    }
    if (i < kN) rowp[i] = s[t] - v;
    if (t == 255) bsum[blockIdx.x] = s[255];
}

__global__ void k_scan2(const int* __restrict__ bsum, int* __restrict__ boff, int nb) {
    __shared__ int s[512];
    int t = threadIdx.x;
    int v = (t < nb) ? bsum[t] : 0;
    s[t] = v;
    __syncthreads();
    for (int off = 1; off < 512; off <<= 1) {
        int add = (t >= off) ? s[t - off] : 0;
        __syncthreads();
        s[t] += add;
        __syncthreads();
    }
    if (t < nb) boff[t] = s[t] - v;
}

__global__ void k_scan3(int* __restrict__ rowp, const int* __restrict__ boff) {
    int i = blockIdx.x * 256 + threadIdx.x;
    if (i < kN) rowp[i] += boff[blockIdx.x];
}

// ---------- CSR fill (by dst): rec[pos] = (src, dinv[src]*dinv[dst]) ----------
__global__ void k_fill(const int* __restrict__ src, const int* __restrict__ dst,
                       const float* __restrict__ dinv,
                       const int* __restrict__ rowp_d, int* __restrict__ cur_d,
                       int2* __restrict__ rec_d) {
    int e = blockIdx.x * blockDim.x + threadIdx.x;
    if (e >= kE) return;
    int s = src[e], d = dst[e];
    float w = dinv[s] * dinv[d];
    int pd = rowp_d[d] + atomicAdd(&cur_d[d], 1);
    rec_d[pd] = make_int2(s, __float_as_int(w));
}

// ---------- GEMM1: hl[N][64] = x[N][256] @ W1[256][64], fp16 store ----------
__global__ __launch_bounds__(256) void k_gemm1(const float* __restrict__ x,
                                               const float* __restrict__ W1,
                                               __half* __restrict__ hl) {
    constexpr int TM = 64;
    constexpr int KC = 32;
    __shared__ float xs[TM][36];
    __shared__ float ws[KC][kH];
    int t = threadIdx.x;
    int tx = t & 15;
    int ty = t >> 4;
    int nb = blockIdx.x * TM;
    float acc[4][4] = {};
    for (int k0 = 0; k0 < kD; k0 += KC) {
        #pragma unroll
        for (int j = 0; j < 2; ++j) {
            int id = t * 2 + j;
            int row = id >> 3;
            int c4 = (id & 7) * 4;
            int node = nb + row;
            if (node >= kN) node = kN - 1;
            float4 v = *(const float4*)(x + (size_t)node * kD + k0 + c4);
            *(float4*)&xs[row][c4] = v;
        }
        #pragma unroll
        for (int j = 0; j < 2; ++j) {
            int id = t * 2 + j;
            int row = id >> 4;
            int c4 = (id & 15) * 4;
            float4 v = *(const float4*)(W1 + (size_t)(k0 + row) * kH + c4);
            *(float4*)&ws[row][c4] = v;
        }
        __syncthreads();
        #pragma unroll
        for (int kk = 0; kk < KC; ++kk) {
            float a0 = xs[ty * 4 + 0][kk];
            float a1 = xs[ty * 4 + 1][kk];
            float a2 = xs[ty * 4 + 2][kk];
            float a3 = xs[ty * 4 + 3][kk];
            float4 b = *(const float4*)&ws[kk][tx * 4];
            acc[0][0] = fmaf(a0, b.x, acc[0][0]); acc[0][1] = fmaf(a0, b.y, acc[0][1]);
            acc[0][2] = fmaf(a0, b.z, acc[0][2]); acc[0][3] = fmaf(a0, b.w, acc[0][3]);
            acc[1][0] = fmaf(a1, b.x, acc[1][0]); acc[1][1] = fmaf(a1, b.y, acc[1][1]);
            acc[1][2] = fmaf(a1, b.z, acc[1][2]); acc[1][3] = fmaf(a1, b.w, acc[1][3]);
            acc[2][0] = fmaf(a2, b.x, acc[2][0]); acc[2][1] = fmaf(a2, b.y, acc[2][1]);
            acc[2][2] = fmaf(a2, b.z, acc[2][2]); acc[2][3] = fmaf(a2, b.w, acc[2][3]);
            acc[3][0] = fmaf(a3, b.x, acc[3][0]); acc[3][1] = fmaf(a3, b.y, acc[3][1]);
            acc[3][2] = fmaf(a3, b.z, acc[3][2]); acc[3][3] = fmaf(a3, b.w, acc[3][3]);
        }
        __syncthreads();
    }
    #pragma unroll
    for (int i = 0; i < 4; ++i) {
        int node = nb + ty * 4 + i;
        if (node < kN) {
            __half2 p0 = __floats2half2_rn(acc[i][0], acc[i][1]);
            __half2 p1 = __floats2half2_rn(acc[i][2], acc[i][3]);
            __half2* dst2 = (__half2*)(hl + (size_t)node * kH + tx * 4);
            dst2[0] = p0;
            dst2[1] = p1;
        }
    }
}

// ---------- conv1: h = relu(Ahat @ hl + b1) ----------
// One wave per node. 8 edge slots x 8 feature-octets: lane = slot*8 + fl.
// No shuffles in the hot loop; 8 gathered rows in flight per iteration.
__global__ __launch_bounds__(256) void k_conv1(const int2* __restrict__ rec,
                                               const int* __restrict__ rowp,
                                               const int* __restrict__ cnt,
                                               const float* __restrict__ dinv,
                                               const __half* __restrict__ hl,
                                               const float* __restrict__ b1,
                                               __half* __restrict__ h) {
    int tid = threadIdx.x;
    int lane = tid & 63;
    int node = blockIdx.x * 4 + (tid >> 6);
    if (node >= kN) return;
    int slot = lane >> 3;
    int fl = lane & 7;
    int base = rowp[node], len = cnt[node];
    float acc[8] = {};
    for (int c0 = 0; c0 < len; c0 += 8) {
        int e = c0 + slot;
        int2 r = make_int2(0, 0);
        if (e < len) r = rec[base + e];
        float w = __int_as_float(r.y);
        uint4 v = *(const uint4*)(hl + ((size_t)r.x << 6) + fl * 8);
        fma8(acc, w, v);
    }
    // reduce partial sums across the 8 slots
    #pragma unroll
    for (int d = 8; d < 64; d <<= 1) {
        #pragma unroll
        for (int j = 0; j < 8; ++j) acc[j] += __shfl_xor(acc[j], d, 64);
    }
    if (slot == 0) {
        float di = dinv[node], d2 = di * di;
        uint4 sv = *(const uint4*)(hl + ((size_t)node << 6) + fl * 8);
        fma8(acc, d2, sv);                       // self-loop
        float4 ba = *(const float4*)(b1 + fl * 8);
        float4 bb = *(const float4*)(b1 + fl * 8 + 4);
        float bz[8] = {ba.x, ba.y, ba.z, ba.w, bb.x, bb.y, bb.z, bb.w};
        __half2 o[4];
        #pragma unroll
        for (int j = 0; j < 4; ++j)
            o[j] = __floats2half2_rn(fmaxf(acc[2 * j] + bz[2 * j], 0.f),
                                     fmaxf(acc[2 * j + 1] + bz[2 * j + 1], 0.f));
        *(uint4*)(h + ((size_t)node << 6) + fl * 8) = *(const uint4*)o;
    }
}

// ---------- pool: q_raw[g] += Ahat-aggregated h rows (dst-CSR, batch-sorted) ----------
// Same 8x8 slot layout; per-slot partial graph sums in registers, flush at
// graph boundaries (rare) with a cross-slot reduce + 8-lane global atomics.
__global__ __launch_bounds__(256) void k_pool3(const int2* __restrict__ rec,
                                               const int* __restrict__ rowp,
                                               const int* __restrict__ cnt,
                                               const float* __restrict__ dinv,
                                               const __half* __restrict__ h,
                                               const int* __restrict__ batch,
                                               float* __restrict__ q_raw) {
    constexpr int CHUNK = 8;
    int tid = threadIdx.x;
    int lane = tid & 63;
    int wid = blockIdx.x * 4 + (tid >> 6);
    int n0 = wid * CHUNK;
    if (n0 >= kN) return;
    int n1 = n0 + CHUNK; if (n1 > kN) n1 = kN;
    int slot = lane >> 3;
    int fl = lane & 7;
    float racc[8] = {};
    int gcur = batch[n0];
    for (int i = n0; i < n1; ++i) {
        int g = batch[i];
        if (g != gcur) {
            // flush: cross-slot reduce then one atomic per feature from lanes 0-7
            #pragma unroll
            for (int d = 8; d < 64; d <<= 1) {
                #pragma unroll
                for (int j = 0; j < 8; ++j) racc[j] += __shfl_xor(racc[j], d, 64);
            }
            if (lane < 8) {
                #pragma unroll
                for (int j = 0; j < 8; ++j)
                    atomicAdd(&q_raw[(gcur << 6) + fl * 8 + j], racc[j]);
            }
            #pragma unroll
            for (int j = 0; j < 8; ++j) racc[j] = 0.f;
            gcur = g;
        }
        int base = rowp[i], len = cnt[i];
        for (int c0 = 0; c0 < len; c0 += 8) {
            int e = c0 + slot;
            int2 r = make_int2(0, 0);
            if (e < len) r = rec[base + e];
            float w = __int_as_float(r.y);
            uint4 v = *(const uint4*)(h + ((size_t)r.x << 6) + fl * 8);
            fma8(racc, w, v);
        }
        if (slot == 0) {                          // self-loop term (slot 0 only)
            float di = dinv[i], d2 = di * di;
            uint4 sv = *(const uint4*)(h + ((size_t)i << 6) + fl * 8);
            fma8(racc, d2, sv);
        }
    }
    #pragma unroll
    for (int d = 8; d < 64; d <<= 1) {
        #pragma unroll
        for (int j = 0; j < 8; ++j) racc[j] += __shfl_xor(racc[j], d, 64);
    }
    if (lane < 8) {
        #pragma unroll
        for (int j = 0; j < 8; ++j)
            atomicAdd(&q_raw[(gcur << 6) + fl * 8 + j], racc[j]);
    }
}

// ---------- head: z_pool = (q_raw/cnt)@W2 + b2 ; decoder MLP ----------
__global__ __launch_bounds__(64) void k_head(const float* __restrict__ q_raw,
                                             const int* __restrict__ gcnt,
                                             const float* __restrict__ W2,
                                             const float* __restrict__ b2,
                                             const float* __restrict__ Wd1,
                                             const float* __restrict__ bd1,
                                             const float* __restrict__ Wd2,
                                             const float* __restrict__ bd2,
                                             float* __restrict__ out) {
    __shared__ float zm[kH], zp[kH], tt[kH];
    int g = blockIdx.x, c = threadIdx.x;
    int cg = gcnt[g];
    float inv = (cg > 0) ? 1.f / (float)cg : 0.f;
    zm[c] = q_raw[(size_t)g * kH + c] * inv;
    __syncthreads();
    float a = b2[c];
    #pragma unroll 8
    for (int k = 0; k < kH; ++k) a = fmaf(zm[k], W2[k * kH + c], a);
    if (cg == 0) a = 0.f;
    out[(size_t)kG * kD + (size_t)g * kH + c] = a;   // z_pool
    zp[c] = a;
    __syncthreads();
    float t = bd1[c];
    #pragma unroll 8
    for (int k = 0; k < kH; ++k) t = fmaf(zp[k], Wd1[k * 64 + c], t);
    tt[c] = fmaxf(t, 0.f);
    __syncthreads();
    #pragma unroll
    for (int j4 = 0; j4 < 4; ++j4) {
        int col = c + j4 * 64;
        float v = bd2[col];
        #pragma unroll 8
        for (int k = 0; k < 64; ++k) v = fmaf(tt[k], Wd2[k * kD + col], v);
        out[(size_t)g * kD + col] = v;               // x_hat
    }
}

extern "C" void kernel_launch(void* const* d_in, const int* in_sizes, int n_in,
                              void* d_out, int out_size, void* d_ws, size_t ws_size,
                              hipStream_t stream) {
    const float* x    = (const float*)d_in[0];
    const int*   ei   = (const int*)d_in[1];
    const int*   src  = ei;
    const int*   dst  = ei + kE;
    const int*   batch= (const int*)d_in[2];
    const float* W1   = (const float*)d_in[3];
    const float* b1   = (const float*)d_in[4];
    const float* W2   = (const float*)d_in[5];
    const float* b2   = (const float*)d_in[6];
    const float* Wd1  = (const float*)d_in[7];
    const float* bd1  = (const float*)d_in[8];
    const float* Wd2  = (const float*)d_in[9];
    const float* bd2  = (const float*)d_in[10];
    float* out = (float*)d_out;

    char* ws = (char*)d_ws;
    int*     cnt_d  = (int*)(ws + OFF_CNTD);
    int*     cur_d  = (int*)(ws + OFF_CURD);
    int*     gcnt   = (int*)(ws + OFF_GCNT);
    float*   q_raw  = (float*)(ws + OFF_QRAW);
    float*   dinv   = (float*)(ws + OFF_DINV);
    int*     rowp_d = (int*)(ws + OFF_ROWPD);
    int*     bsum   = (int*)(ws + OFF_BSUM);
    int*     boff   = (int*)(ws + OFF_BOFF);
    int2*    rec_d  = (int2*)(ws + OFF_RECD);
    __half*  hl     = (__half*)(ws + OFF_HL);
    __half*  h      = (__half*)(ws + OFF_H2);

    hipMemsetAsync(d_ws, 0, ZERO_BYTES, stream);

    const int nScanBlocks = (kN + 255) / 256;  // 391

    k_hist<<<(kE + 255) / 256, 256, 0, stream>>>(dst, cnt_d);
    k_gcnt<<<128, 256, 0, stream>>>(batch, gcnt);
    k_dinv<<<nScanBlocks, 256, 0, stream>>>(cnt_d, dinv);

    k_scan1<<<nScanBlocks, 256, 0, stream>>>(cnt_d, rowp_d, bsum);
    k_scan2<<<1, 512, 0, stream>>>(bsum, boff, nScanBlocks);
    k_scan3<<<nScanBlocks, 256, 0, stream>>>(rowp_d, boff);

    k_fill<<<(kE + 255) / 256, 256, 0, stream>>>(src, dst, dinv, rowp_d, cur_d, rec_d);

    k_gemm1<<<(kN + 63) / 64, 256, 0, stream>>>(x, W1, hl);

    k_conv1<<<(kN + 3) / 4, 256, 0, stream>>>(rec_d, rowp_d, cnt_d, dinv, hl, b1, h);

    k_pool3<<<(kN / 8 + 3) / 4, 256, 0, stream>>>(rec_d, rowp_d, cnt_d, dinv, h, batch, q_raw);

    k_head<<<kG, 64, 0, stream>>>(q_raw, gcnt, W2, b2, Wd1, bd1, Wd2, bd2, out);
}

// Round 4
// 466.859 us; speedup vs baseline: 3.9309x; 1.2039x over previous
//
#include <hip/hip_runtime.h>
#include <hip/hip_bf16.h>
#include <hip/hip_fp16.h>

namespace {
constexpr int kN = 100000;   // nodes
constexpr int kE = 3200000;  // edges
constexpr int kD = 256;      // node_dim
constexpr int kH = 64;       // hidden = latent = 64
constexpr int kG = 128;      // graphs

constexpr size_t kAlign = 512;
constexpr size_t align_up(size_t v) { return (v + kAlign - 1) & ~(kAlign - 1); }

constexpr size_t SZ_N_I   = align_up((size_t)kN * 4);
// ---- zeroed region ----
constexpr size_t OFF_CNTD = 0;                           // int[N]  in-degree (dst)
constexpr size_t OFF_GCNT = OFF_CNTD + SZ_N_I;           // int[G]
constexpr size_t OFF_QRAW = OFF_GCNT + kAlign;           // f32[G*H]
constexpr size_t ZERO_BYTES = OFF_QRAW + align_up((size_t)kG * kH * 4);
// ---- rest ----
constexpr size_t OFF_DINV  = ZERO_BYTES;                 // f32[N]
constexpr size_t OFF_ROWPD = OFF_DINV + SZ_N_I;          // int[N]
constexpr size_t OFF_BSUM  = OFF_ROWPD + SZ_N_I;         // int[512]
constexpr size_t OFF_BOFF  = OFF_BSUM + 4096;            // int[512]
constexpr size_t OFF_SLOT  = OFF_BOFF + 4096;            // int[E] per-edge rank within dst
constexpr size_t OFF_RECD  = OFF_SLOT + align_up((size_t)kE * 4);  // int[E] src ids, by dst
// feature tables have kN+1 rows: row kN is an all-zero sentinel for pad slots
constexpr size_t OFF_HL    = OFF_RECD + align_up((size_t)kE * 4);            // fp16[(N+1)*64] dinv*x@W1
constexpr size_t OFF_H2    = OFF_HL + align_up((size_t)(kN + 1) * kH * 2);   // fp16[(N+1)*64] dinv*relu(conv1)
} // namespace

// add 8 fp16 features (as uint4) into 8 f32 accumulators
__device__ __forceinline__ void add8(float (&acc)[8], uint4 u) {
    const __half2* hp = (const __half2*)&u;
    #pragma unroll
    for (int j = 0; j < 4; ++j) {
        float2 f = __half22float2(hp[j]);
        acc[2 * j]     += f.x;
        acc[2 * j + 1] += f.y;
    }
}

// ---------- degree histogram over dst; also records each edge's rank ----------
__global__ void k_hist(const int* __restrict__ dst, int* __restrict__ cnt_d,
                       int* __restrict__ slot) {
    int e = blockIdx.x * blockDim.x + threadIdx.x;
    if (e < kE) slot[e] = atomicAdd(&cnt_d[dst[e]], 1);
}

// ---------- per-graph node counts (batch sorted; LDS-aggregated) ----------
__global__ void k_gcnt(const int* __restrict__ batch, int* __restrict__ gcnt) {
    __shared__ int h[kG];
    int t = threadIdx.x;
    if (t < kG) h[t] = 0;
    __syncthreads();
    for (int i = blockIdx.x * blockDim.x + t; i < kN; i += gridDim.x * blockDim.x)
        atomicAdd(&h[batch[i]], 1);
    __syncthreads();
    if (t < kG && h[t]) atomicAdd(&gcnt[t], h[t]);
}

// ---------- dinv = rsqrt(indeg + 1); also zero the sentinel rows ----------
__global__ void k_dinv(const int* __restrict__ cnt, float* __restrict__ dinv,
                       __half* __restrict__ hl, __half* __restrict__ h) {
    int i = blockIdx.x * blockDim.x + threadIdx.x;
    if (i < kN) dinv[i] = rsqrtf((float)(cnt[i] + 1));
    if (blockIdx.x == 0 && threadIdx.x < kH) {
        hl[(size_t)kN * kH + threadIdx.x] = __float2half(0.f);
        h [(size_t)kN * kH + threadIdx.x] = __float2half(0.f);
    }
}

// ---------- exclusive scan of counts -> row_ptr (3 kernels) ----------
__global__ void k_scan1(const int* __restrict__ cnt, int* __restrict__ rowp,
                        int* __restrict__ bsum) {
    __shared__ int s[256];
    int t = threadIdx.x;
    int i = blockIdx.x * 256 + t;
    int v = (i < kN) ? cnt[i] : 0;
    s[t] = v;
    __syncthreads();
    for (int off = 1; off < 256; off <<= 1) {
        int add = (t >= off) ? s[t - off] : 0;
        __syncthreads();
        s[t] += add;
        __syncthreads();
    }
    if (i < kN) rowp[i] = s[t] - v;
    if (t == 255) bsum[blockIdx.x] = s[255];
}

__global__ void k_scan2(const int* __restrict__ bsum, int* __restrict__ boff, int nb) {
    __shared__ int s[512];
    int t = threadIdx.x;
    int v = (t < nb) ? bsum[t] : 0;
    s[t] = v;
    __syncthreads();
    for (int off = 1; off < 512; off <<= 1) {
        int add = (t >= off) ? s[t - off] : 0;
        __syncthreads();
        s[t] += add;
        __syncthreads();
    }
    if (t < nb) boff[t] = s[t] - v;
}

__global__ void k_scan3(int* __restrict__ rowp, const int* __restrict__ boff) {
    int i = blockIdx.x * 256 + threadIdx.x;
    if (i < kN) rowp[i] += boff[blockIdx.x];
}

// ---------- CSR fill (by dst), atomic-free: pos = rowp[dst] + slot ----------
__global__ void k_fill(const int* __restrict__ src, const int* __restrict__ dst,
                       const int* __restrict__ slot, const int* __restrict__ rowp_d,
                       int* __restrict__ rec_d) {
    int e = blockIdx.x * blockDim.x + threadIdx.x;
    if (e >= kE) return;
    rec_d[rowp_d[dst[e]] + slot[e]] = src[e];
}

// ---------- GEMM1: hl'[N][64] = dinv * (x[N][256] @ W1[256][64]), fp16 ----------
__global__ __launch_bounds__(256) void k_gemm1(const float* __restrict__ x,
                                               const float* __restrict__ W1,
                                               const float* __restrict__ dinv,
                                               __half* __restrict__ hl) {
    constexpr int TM = 64;
    constexpr int KC = 32;
    __shared__ float xs[TM][36];
    __shared__ float ws[KC][kH];
    int t = threadIdx.x;
    int tx = t & 15;
    int ty = t >> 4;
    int nb = blockIdx.x * TM;
    float acc[4][4] = {};
    for (int k0 = 0; k0 < kD; k0 += KC) {
        #pragma unroll
        for (int j = 0; j < 2; ++j) {
            int id = t * 2 + j;
            int row = id >> 3;
            int c4 = (id & 7) * 4;
            int node = nb + row;
            if (node >= kN) node = kN - 1;
            float4 v = *(const float4*)(x + (size_t)node * kD + k0 + c4);
            *(float4*)&xs[row][c4] = v;
        }
        #pragma unroll
        for (int j = 0; j < 2; ++j) {
            int id = t * 2 + j;
            int row = id >> 4;
            int c4 = (id & 15) * 4;
            float4 v = *(const float4*)(W1 + (size_t)(k0 + row) * kH + c4);
            *(float4*)&ws[row][c4] = v;
        }
        __syncthreads();
        #pragma unroll
        for (int kk = 0; kk < KC; ++kk) {
            float a0 = xs[ty * 4 + 0][kk];
            float a1 = xs[ty * 4 + 1][kk];
            float a2 = xs[ty * 4 + 2][kk];
            float a3 = xs[ty * 4 + 3][kk];
            float4 b = *(const float4*)&ws[kk][tx * 4];
            acc[0][0] = fmaf(a0, b.x, acc[0][0]); acc[0][1] = fmaf(a0, b.y, acc[0][1]);
            acc[0][2] = fmaf(a0, b.z, acc[0][2]); acc[0][3] = fmaf(a0, b.w, acc[0][3]);
            acc[1][0] = fmaf(a1, b.x, acc[1][0]); acc[1][1] = fmaf(a1, b.y, acc[1][1]);
            acc[1][2] = fmaf(a1, b.z, acc[1][2]); acc[1][3] = fmaf(a1, b.w, acc[1][3]);
            acc[2][0] = fmaf(a2, b.x, acc[2][0]); acc[2][1] = fmaf(a2, b.y, acc[2][1]);
            acc[2][2] = fmaf(a2, b.z, acc[2][2]); acc[2][3] = fmaf(a2, b.w, acc[2][3]);
            acc[3][0] = fmaf(a3, b.x, acc[3][0]); acc[3][1] = fmaf(a3, b.y, acc[3][1]);
            acc[3][2] = fmaf(a3, b.z, acc[3][2]); acc[3][3] = fmaf(a3, b.w, acc[3][3]);
        }
        __syncthreads();
    }
    #pragma unroll
    for (int i = 0; i < 4; ++i) {
        int node = nb + ty * 4 + i;
        if (node < kN) {
            float di = dinv[node];
            __half2 p0 = __floats2half2_rn(di * acc[i][0], di * acc[i][1]);
            __half2 p1 = __floats2half2_rn(di * acc[i][2], di * acc[i][3]);
            __half2* dst2 = (__half2*)(hl + (size_t)node * kH + tx * 4);
            dst2[0] = p0;
            dst2[1] = p1;
        }
    }
}

// ---------- conv1: h' = dinv * relu(dinv*(sum hl'[s] + hl'[d]) + b1) ----------
// One wave per node. 8 edge slots x 8 feature-octets: lane = slot*8 + fl.
// Unweighted sum: pad slots read the zero sentinel row (index kN).
__global__ __launch_bounds__(256) void k_conv1(const int* __restrict__ rec,
                                               const int* __restrict__ rowp,
                                               const int* __restrict__ cnt,
                                               const float* __restrict__ dinv,
                                               const __half* __restrict__ hl,
                                               const float* __restrict__ b1,
                                               __half* __restrict__ h) {
    int tid = threadIdx.x;
    int lane = tid & 63;
    int node = blockIdx.x * 4 + (tid >> 6);
    if (node >= kN) return;
    int slot = lane >> 3;
    int fl = lane & 7;
    int base = rowp[node], len = cnt[node];
    float acc[8] = {};
    for (int c0 = 0; c0 < len; c0 += 8) {
        int e = c0 + slot;
        int sidx = (e < len) ? rec[base + e] : kN;
        uint4 v = *(const uint4*)(hl + ((size_t)sidx << 6) + fl * 8);
        add8(acc, v);
    }
    // reduce partial sums across the 8 slots
    #pragma unroll
    for (int d = 8; d < 64; d <<= 1) {
        #pragma unroll
        for (int j = 0; j < 8; ++j) acc[j] += __shfl_xor(acc[j], d, 64);
    }
    if (slot == 0) {
        uint4 sv = *(const uint4*)(hl + ((size_t)node << 6) + fl * 8);
        add8(acc, sv);                            // self-loop (hl' already dinv-scaled)
        float di = dinv[node];
        float4 ba = *(const float4*)(b1 + fl * 8);
        float4 bb = *(const float4*)(b1 + fl * 8 + 4);
        float bz[8] = {ba.x, ba.y, ba.z, ba.w, bb.x, bb.y, bb.z, bb.w};
        __half2 o[4];
        #pragma unroll
        for (int j = 0; j < 4; ++j)
            o[j] = __floats2half2_rn(
                di * fmaxf(fmaf(di, acc[2 * j], bz[2 * j]), 0.f),
                di * fmaxf(fmaf(di, acc[2 * j + 1], bz[2 * j + 1]), 0.f));
        *(uint4*)(h + ((size_t)node << 6) + fl * 8) = *(const uint4*)o;
    }
}

// ---------- pool: q_raw[g] += dinv[i]*(sum h'[s] + h'[i])  (batch-sorted) ----------
__global__ __launch_bounds__(256) void k_pool3(const int* __restrict__ rec,
                                               const int* __restrict__ rowp,
                                               const int* __restrict__ cnt,
                                               const float* __restrict__ dinv,
                                               const __half* __restrict__ h,
                                               const int* __restrict__ batch,
                                               float* __restrict__ q_raw) {
    constexpr int CHUNK = 8;
    int tid = threadIdx.x;
    int lane = tid & 63;
    int wid = blockIdx.x * 4 + (tid >> 6);
    int n0 = wid * CHUNK;
    if (n0 >= kN) return;
    int n1 = n0 + CHUNK; if (n1 > kN) n1 = kN;
    int slot = lane >> 3;
    int fl = lane & 7;
    float racc[8] = {};
    int gcur = batch[n0];
    for (int i = n0; i < n1; ++i) {
        int g = batch[i];
        if (g != gcur) {
            #pragma unroll
            for (int d = 8; d < 64; d <<= 1) {
                #pragma unroll
                for (int j = 0; j < 8; ++j) racc[j] += __shfl_xor(racc[j], d, 64);
            }
            if (lane < 8) {
                #pragma unroll
                for (int j = 0; j < 8; ++j)
                    atomicAdd(&q_raw[(gcur << 6) + fl * 8 + j], racc[j]);
            }
            #pragma unroll
            for (int j = 0; j < 8; ++j) racc[j] = 0.f;
            gcur = g;
        }
        int base = rowp[i], len = cnt[i];
        float ns[8] = {};
        for (int c0 = 0; c0 < len; c0 += 8) {
            int e = c0 + slot;
            int sidx = (e < len) ? rec[base + e] : kN;
            uint4 v = *(const uint4*)(h + ((size_t)sidx << 6) + fl * 8);
            add8(ns, v);
        }
        if (slot == 0) {                          // self-loop term
            uint4 sv = *(const uint4*)(h + ((size_t)i << 6) + fl * 8);
            add8(ns, sv);
        }
        float di = dinv[i];
        #pragma unroll
        for (int j = 0; j < 8; ++j) racc[j] = fmaf(di, ns[j], racc[j]);
    }
    #pragma unroll
    for (int d = 8; d < 64; d <<= 1) {
        #pragma unroll
        for (int j = 0; j < 8; ++j) racc[j] += __shfl_xor(racc[j], d, 64);
    }
    if (lane < 8) {
        #pragma unroll
        for (int j = 0; j < 8; ++j)
            atomicAdd(&q_raw[(gcur << 6) + fl * 8 + j], racc[j]);
    }
}

// ---------- head: z_pool = (q_raw/cnt)@W2 + b2 ; decoder MLP ----------
__global__ __launch_bounds__(64) void k_head(const float* __restrict__ q_raw,
                                             const int* __restrict__ gcnt,
                                             const float* __restrict__ W2,
                                             const float* __restrict__ b2,
                                             const float* __restrict__ Wd1,
                                             const float* __restrict__ bd1,
                                             const float* __restrict__ Wd2,
                                             const float* __restrict__ bd2,
                                             float* __restrict__ out) {
    __shared__ float zm[kH], zp[kH], tt[kH];
    int g = blockIdx.x, c = threadIdx.x;
    int cg = gcnt[g];
    float inv = (cg > 0) ? 1.f / (float)cg : 0.f;
    zm[c] = q_raw[(size_t)g * kH + c] * inv;
    __syncthreads();
    float a = b2[c];
    #pragma unroll 8
    for (int k = 0; k < kH; ++k) a = fmaf(zm[k], W2[k * kH + c], a);
    if (cg == 0) a = 0.f;
    out[(size_t)kG * kD + (size_t)g * kH + c] = a;   // z_pool
    zp[c] = a;
    __syncthreads();
    float t = bd1[c];
    #pragma unroll 8
    for (int k = 0; k < kH; ++k) t = fmaf(zp[k], Wd1[k * 64 + c], t);
    tt[c] = fmaxf(t, 0.f);
    __syncthreads();
    #pragma unroll
    for (int j4 = 0; j4 < 4; ++j4) {
        int col = c + j4 * 64;
        float v = bd2[col];
        #pragma unroll 8
        for (int k = 0; k < 64; ++k) v = fmaf(tt[k], Wd2[k * kD + col], v);
        out[(size_t)g * kD + col] = v;               // x_hat
    }
}

extern "C" void kernel_launch(void* const* d_in, const int* in_sizes, int n_in,
                              void* d_out, int out_size, void* d_ws, size_t ws_size,
                              hipStream_t stream) {
    const float* x    = (const float*)d_in[0];
    const int*   ei   = (const int*)d_in[1];
    const int*   src  = ei;
    const int*   dst  = ei + kE;
    const int*   batch= (const int*)d_in[2];
    const float* W1   = (const float*)d_in[3];
    const float* b1   = (const float*)d_in[4];
    const float* W2   = (const float*)d_in[5];
    const float* b2   = (const float*)d_in[6];
    const float* Wd1  = (const float*)d_in[7];
    const float* bd1  = (const float*)d_in[8];
    const float* Wd2  = (const float*)d_in[9];
    const float* bd2  = (const float*)d_in[10];
    float* out = (float*)d_out;

    char* ws = (char*)d_ws;
    int*     cnt_d  = (int*)(ws + OFF_CNTD);
    int*     gcnt   = (int*)(ws + OFF_GCNT);
    float*   q_raw  = (float*)(ws + OFF_QRAW);
    float*   dinv   = (float*)(ws + OFF_DINV);
    int*     rowp_d = (int*)(ws + OFF_ROWPD);
    int*     bsum   = (int*)(ws + OFF_BSUM);
    int*     boff   = (int*)(ws + OFF_BOFF);
    int*     slot   = (int*)(ws + OFF_SLOT);
    int*     rec_d  = (int*)(ws + OFF_RECD);
    __half*  hl     = (__half*)(ws + OFF_HL);
    __half*  h      = (__half*)(ws + OFF_H2);

    hipMemsetAsync(d_ws, 0, ZERO_BYTES, stream);

    const int nScanBlocks = (kN + 255) / 256;  // 391

    k_hist<<<(kE + 255) / 256, 256, 0, stream>>>(dst, cnt_d, slot);
    k_gcnt<<<128, 256, 0, stream>>>(batch, gcnt);
    k_dinv<<<nScanBlocks, 256, 0, stream>>>(cnt_d, dinv, hl, h);

    k_scan1<<<nScanBlocks, 256, 0, stream>>>(cnt_d, rowp_d, bsum);
    k_scan2<<<1, 512, 0, stream>>>(bsum, boff, nScanBlocks);
    k_scan3<<<nScanBlocks, 256, 0, stream>>>(rowp_d, boff);

    k_fill<<<(kE + 255) / 256, 256, 0, stream>>>(src, dst, slot, rowp_d, rec_d);

    k_gemm1<<<(kN + 63) / 64, 256, 0, stream>>>(x, W1, dinv, hl);

    k_conv1<<<(kN + 3) / 4, 256, 0, stream>>>(rec_d, rowp_d, cnt_d, dinv, hl, b1, h);

    k_pool3<<<(kN / 8 + 3) / 4, 256, 0, stream>>>(rec_d, rowp_d, cnt_d, dinv, h, batch, q_raw);

    k_head<<<kG, 64, 0, stream>>>(q_raw, gcnt, W2, b2, Wd1, bd1, Wd2, bd2, out);
}

// Round 5
// 455.863 us; speedup vs baseline: 4.0257x; 1.0241x over previous
//
#include <hip/hip_runtime.h>
#include <hip/hip_bf16.h>
#include <hip/hip_fp16.h>

namespace {
constexpr int kN = 100000;   // nodes
constexpr int kE = 3200000;  // edges
constexpr int kD = 256;      // node_dim
constexpr int kH = 64;       // hidden = latent = 64
constexpr int kG = 128;      // graphs
constexpr int kPad = 16;     // ints per counter line (64 B): one counter per L2 line

constexpr size_t kAlign = 512;
constexpr size_t align_up(size_t v) { return (v + kAlign - 1) & ~(kAlign - 1); }

constexpr size_t SZ_N_I   = align_up((size_t)kN * 4);
// ---- zeroed region ----
constexpr size_t OFF_CNTP = 0;                           // int[N*16] padded degree counters
constexpr size_t OFF_GCNT = OFF_CNTP + align_up((size_t)kN * kPad * 4);  // int[G]
constexpr size_t OFF_QRAW = OFF_GCNT + kAlign;           // f32[G*H]
constexpr size_t ZERO_BYTES = OFF_QRAW + align_up((size_t)kG * kH * 4);
// ---- rest ----
constexpr size_t OFF_DINV  = ZERO_BYTES;                 // f32[N]
constexpr size_t OFF_CNTC  = OFF_DINV + SZ_N_I;          // int[N] compact degrees
constexpr size_t OFF_ROWPD = OFF_CNTC + SZ_N_I;          // int[N]
constexpr size_t OFF_BSUM  = OFF_ROWPD + SZ_N_I;         // int[512]
constexpr size_t OFF_BOFF  = OFF_BSUM + 4096;            // int[512]
constexpr size_t OFF_SLOT  = OFF_BOFF + 4096;            // int[E] per-edge rank within dst
constexpr size_t OFF_RECD  = OFF_SLOT + align_up((size_t)kE * 4);  // int[E] src ids, by dst
// feature tables have kN+1 rows: row kN is an all-zero sentinel for pad slots
constexpr size_t OFF_HL    = OFF_RECD + align_up((size_t)kE * 4);            // fp16[(N+1)*64] dinv*x@W1
constexpr size_t OFF_H2    = OFF_HL + align_up((size_t)(kN + 1) * kH * 2);   // fp16[(N+1)*64] dinv*relu(conv1)
} // namespace

// add 8 fp16 features (as uint4) into 8 f32 accumulators
__device__ __forceinline__ void add8(float (&acc)[8], uint4 u) {
    const __half2* hp = (const __half2*)&u;
    #pragma unroll
    for (int j = 0; j < 4; ++j) {
        float2 f = __half22float2(hp[j]);
        acc[2 * j]     += f.x;
        acc[2 * j + 1] += f.y;
    }
}

// ---------- degree histogram over dst (padded counters) + per-edge rank ----------
__global__ void k_hist(const int* __restrict__ dst, int* __restrict__ cnt_p,
                       int* __restrict__ slot) {
    int e = blockIdx.x * blockDim.x + threadIdx.x;
    if (e < kE) slot[e] = atomicAdd(&cnt_p[(size_t)dst[e] << 4], 1);
}

// ---------- per-graph node counts (batch sorted; LDS-aggregated) ----------
__global__ void k_gcnt(const int* __restrict__ batch, int* __restrict__ gcnt) {
    __shared__ int h[kG];
    int t = threadIdx.x;
    if (t < kG) h[t] = 0;
    __syncthreads();
    for (int i = blockIdx.x * blockDim.x + t; i < kN; i += gridDim.x * blockDim.x)
        atomicAdd(&h[batch[i]], 1);
    __syncthreads();
    if (t < kG && h[t]) atomicAdd(&gcnt[t], h[t]);
}

// ---------- compact degrees + dinv = rsqrt(deg+1); zero sentinel rows ----------
__global__ void k_dinv(const int* __restrict__ cnt_p, int* __restrict__ cnt_c,
                       float* __restrict__ dinv,
                       __half* __restrict__ hl, __half* __restrict__ h) {
    int i = blockIdx.x * blockDim.x + threadIdx.x;
    if (i < kN) {
        int c = cnt_p[(size_t)i << 4];
        cnt_c[i] = c;
        dinv[i] = rsqrtf((float)(c + 1));
    }
    if (blockIdx.x == 0 && threadIdx.x < kH) {
        hl[(size_t)kN * kH + threadIdx.x] = __float2half(0.f);
        h [(size_t)kN * kH + threadIdx.x] = __float2half(0.f);
    }
}

// ---------- exclusive scan of compact counts -> row_ptr (3 kernels) ----------
__global__ void k_scan1(const int* __restrict__ cnt, int* __restrict__ rowp,
                        int* __restrict__ bsum) {
    __shared__ int s[256];
    int t = threadIdx.x;
    int i = blockIdx.x * 256 + t;
    int v = (i < kN) ? cnt[i] : 0;
    s[t] = v;
    __syncthreads();
    for (int off = 1; off < 256; off <<= 1) {
        int add = (t >= off) ? s[t - off] : 0;
        __syncthreads();
        s[t] += add;
        __syncthreads();
    }
    if (i < kN) rowp[i] = s[t] - v;
    if (t == 255) bsum[blockIdx.x] = s[255];
}

__global__ void k_scan2(const int* __restrict__ bsum, int* __restrict__ boff, int nb) {
    __shared__ int s[512];
    int t = threadIdx.x;
    int v = (t < nb) ? bsum[t] : 0;
    s[t] = v;
    __syncthreads();
    for (int off = 1; off < 512; off <<= 1) {
        int add = (t >= off) ? s[t - off] : 0;
        __syncthreads();
        s[t] += add;
        __syncthreads();
    }
    if (t < nb) boff[t] = s[t] - v;
}

__global__ void k_scan3(int* __restrict__ rowp, const int* __restrict__ boff) {
    int i = blockIdx.x * 256 + threadIdx.x;
    if (i < kN) rowp[i] += boff[blockIdx.x];
}

// ---------- CSR fill (by dst), atomic-free: pos = rowp[dst] + slot ----------
__global__ void k_fill(const int* __restrict__ src, const int* __restrict__ dst,
                       const int* __restrict__ slot, const int* __restrict__ rowp_d,
                       int* __restrict__ rec_d) {
    int e = blockIdx.x * blockDim.x + threadIdx.x;
    if (e >= kE) return;
    rec_d[rowp_d[dst[e]] + slot[e]] = src[e];
}

// ---------- GEMM1: hl'[N][64] = dinv * (x[N][256] @ W1[256][64]), fp16 ----------
__global__ __launch_bounds__(256) void k_gemm1(const float* __restrict__ x,
                                               const float* __restrict__ W1,
                                               const float* __restrict__ dinv,
                                               __half* __restrict__ hl) {
    constexpr int TM = 64;
    constexpr int KC = 32;
    __shared__ float xs[TM][36];
    __shared__ float ws[KC][kH];
    int t = threadIdx.x;
    int tx = t & 15;
    int ty = t >> 4;
    int nb = blockIdx.x * TM;
    float acc[4][4] = {};
    for (int k0 = 0; k0 < kD; k0 += KC) {
        #pragma unroll
        for (int j = 0; j < 2; ++j) {
            int id = t * 2 + j;
            int row = id >> 3;
            int c4 = (id & 7) * 4;
            int node = nb + row;
            if (node >= kN) node = kN - 1;
            float4 v = *(const float4*)(x + (size_t)node * kD + k0 + c4);
            *(float4*)&xs[row][c4] = v;
        }
        #pragma unroll
        for (int j = 0; j < 2; ++j) {
            int id = t * 2 + j;
            int row = id >> 4;
            int c4 = (id & 15) * 4;
            float4 v = *(const float4*)(W1 + (size_t)(k0 + row) * kH + c4);
            *(float4*)&ws[row][c4] = v;
        }
        __syncthreads();
        #pragma unroll
        for (int kk = 0; kk < KC; ++kk) {
            float a0 = xs[ty * 4 + 0][kk];
            float a1 = xs[ty * 4 + 1][kk];
            float a2 = xs[ty * 4 + 2][kk];
            float a3 = xs[ty * 4 + 3][kk];
            float4 b = *(const float4*)&ws[kk][tx * 4];
            acc[0][0] = fmaf(a0, b.x, acc[0][0]); acc[0][1] = fmaf(a0, b.y, acc[0][1]);
            acc[0][2] = fmaf(a0, b.z, acc[0][2]); acc[0][3] = fmaf(a0, b.w, acc[0][3]);
            acc[1][0] = fmaf(a1, b.x, acc[1][0]); acc[1][1] = fmaf(a1, b.y, acc[1][1]);
            acc[1][2] = fmaf(a1, b.z, acc[1][2]); acc[1][3] = fmaf(a1, b.w, acc[1][3]);
            acc[2][0] = fmaf(a2, b.x, acc[2][0]); acc[2][1] = fmaf(a2, b.y, acc[2][1]);
            acc[2][2] = fmaf(a2, b.z, acc[2][2]); acc[2][3] = fmaf(a2, b.w, acc[2][3]);
            acc[3][0] = fmaf(a3, b.x, acc[3][0]); acc[3][1] = fmaf(a3, b.y, acc[3][1]);
            acc[3][2] = fmaf(a3, b.z, acc[3][2]); acc[3][3] = fmaf(a3, b.w, acc[3][3]);
        }
        __syncthreads();
    }
    #pragma unroll
    for (int i = 0; i < 4; ++i) {
        int node = nb + ty * 4 + i;
        if (node < kN) {
            float di = dinv[node];
            __half2 p0 = __floats2half2_rn(di * acc[i][0], di * acc[i][1]);
            __half2 p1 = __floats2half2_rn(di * acc[i][2], di * acc[i][3]);
            __half2* dst2 = (__half2*)(hl + (size_t)node * kH + tx * 4);
            dst2[0] = p0;
            dst2[1] = p1;
        }
    }
}

// ---------- conv1: h' = dinv * relu(dinv*(sum hl'[s] + hl'[d]) + b1) ----------
// One wave per node; 8 edge slots x 8 feature-octets; 2-deep unrolled gather
// (16 rows in flight per wave). Pad slots read the zero sentinel row kN.
__global__ __launch_bounds__(256) void k_conv1(const int* __restrict__ rec,
                                               const int* __restrict__ rowp,
                                               const int* __restrict__ cnt,
                                               const float* __restrict__ dinv,
                                               const __half* __restrict__ hl,
                                               const float* __restrict__ b1,
                                               __half* __restrict__ h) {
    int tid = threadIdx.x;
    int lane = tid & 63;
    int node = blockIdx.x * 4 + (tid >> 6);
    if (node >= kN) return;
    int slot = lane >> 3;
    int fl = lane & 7;
    int base = rowp[node], len = cnt[node];
    float acc0[8] = {}, acc1[8] = {};
    for (int c0 = 0; c0 < len; c0 += 16) {
        int e0 = c0 + slot;
        int e1 = c0 + 8 + slot;
        int s0 = (e0 < len) ? rec[base + e0] : kN;
        int s1 = (e1 < len) ? rec[base + e1] : kN;
        uint4 v0 = *(const uint4*)(hl + ((size_t)s0 << 6) + fl * 8);
        uint4 v1 = *(const uint4*)(hl + ((size_t)s1 << 6) + fl * 8);
        add8(acc0, v0);
        add8(acc1, v1);
    }
    #pragma unroll
    for (int j = 0; j < 8; ++j) acc0[j] += acc1[j];
    // reduce partial sums across the 8 slots
    #pragma unroll
    for (int d = 8; d < 64; d <<= 1) {
        #pragma unroll
        for (int j = 0; j < 8; ++j) acc0[j] += __shfl_xor(acc0[j], d, 64);
    }
    if (slot == 0) {
        uint4 sv = *(const uint4*)(hl + ((size_t)node << 6) + fl * 8);
        add8(acc0, sv);                           // self-loop (hl' already dinv-scaled)
        float di = dinv[node];
        float4 ba = *(const float4*)(b1 + fl * 8);
        float4 bb = *(const float4*)(b1 + fl * 8 + 4);
        float bz[8] = {ba.x, ba.y, ba.z, ba.w, bb.x, bb.y, bb.z, bb.w};
        __half2 o[4];
        #pragma unroll
        for (int j = 0; j < 4; ++j)
            o[j] = __floats2half2_rn(
                di * fmaxf(fmaf(di, acc0[2 * j], bz[2 * j]), 0.f),
                di * fmaxf(fmaf(di, acc0[2 * j + 1], bz[2 * j + 1]), 0.f));
        *(uint4*)(h + ((size_t)node << 6) + fl * 8) = *(const uint4*)o;
    }
}

// ---------- pool: q_raw[g] += dinv[i]*(sum h'[s] + h'[i])  (batch-sorted) ----------
__global__ __launch_bounds__(256) void k_pool3(const int* __restrict__ rec,
                                               const int* __restrict__ rowp,
                                               const int* __restrict__ cnt,
                                               const float* __restrict__ dinv,
                                               const __half* __restrict__ h,
                                               const int* __restrict__ batch,
                                               float* __restrict__ q_raw) {
    constexpr int CHUNK = 8;
    int tid = threadIdx.x;
    int lane = tid & 63;
    int wid = blockIdx.x * 4 + (tid >> 6);
    int n0 = wid * CHUNK;
    if (n0 >= kN) return;
    int n1 = n0 + CHUNK; if (n1 > kN) n1 = kN;
    int slot = lane >> 3;
    int fl = lane & 7;
    float racc[8] = {};
    int gcur = batch[n0];
    for (int i = n0; i < n1; ++i) {
        int g = batch[i];
        if (g != gcur) {
            #pragma unroll
            for (int d = 8; d < 64; d <<= 1) {
                #pragma unroll
                for (int j = 0; j < 8; ++j) racc[j] += __shfl_xor(racc[j], d, 64);
            }
            if (lane < 8) {
                #pragma unroll
                for (int j = 0; j < 8; ++j)
                    atomicAdd(&q_raw[(gcur << 6) + fl * 8 + j], racc[j]);
            }
            #pragma unroll
            for (int j = 0; j < 8; ++j) racc[j] = 0.f;
            gcur = g;
        }
        int base = rowp[i], len = cnt[i];
        float ns0[8] = {}, ns1[8] = {};
        for (int c0 = 0; c0 < len; c0 += 16) {
            int e0 = c0 + slot;
            int e1 = c0 + 8 + slot;
            int s0 = (e0 < len) ? rec[base + e0] : kN;
            int s1 = (e1 < len) ? rec[base + e1] : kN;
            uint4 v0 = *(const uint4*)(h + ((size_t)s0 << 6) + fl * 8);
            uint4 v1 = *(const uint4*)(h + ((size_t)s1 << 6) + fl * 8);
            add8(ns0, v0);
            add8(ns1, v1);
        }
        if (slot == 0) {                          // self-loop term
            uint4 sv = *(const uint4*)(h + ((size_t)i << 6) + fl * 8);
            add8(ns0, sv);
        }
        float di = dinv[i];
        #pragma unroll
        for (int j = 0; j < 8; ++j) racc[j] = fmaf(di, ns0[j] + ns1[j], racc[j]);
    }
    #pragma unroll
    for (int d = 8; d < 64; d <<= 1) {
        #pragma unroll
        for (int j = 0; j < 8; ++j) racc[j] += __shfl_xor(racc[j], d, 64);
    }
    if (lane < 8) {
        #pragma unroll
        for (int j = 0; j < 8; ++j)
            atomicAdd(&q_raw[(gcur << 6) + fl * 8 + j], racc[j]);
    }
}

// ---------- head: z_pool = (q_raw/cnt)@W2 + b2 ; decoder MLP ----------
__global__ __launch_bounds__(64) void k_head(const float* __restrict__ q_raw,
                                             const int* __restrict__ gcnt,
                                             const float* __restrict__ W2,
                                             const float* __restrict__ b2,
                                             const float* __restrict__ Wd1,
                                             const float* __restrict__ bd1,
                                             const float* __restrict__ Wd2,
                                             const float* __restrict__ bd2,
                                             float* __restrict__ out) {
    __shared__ float zm[kH], zp[kH], tt[kH];
    int g = blockIdx.x, c = threadIdx.x;
    int cg = gcnt[g];
    float inv = (cg > 0) ? 1.f / (float)cg : 0.f;
    zm[c] = q_raw[(size_t)g * kH + c] * inv;
    __syncthreads();
    float a = b2[c];
    #pragma unroll 8
    for (int k = 0; k < kH; ++k) a = fmaf(zm[k], W2[k * kH + c], a);
    if (cg == 0) a = 0.f;
    out[(size_t)kG * kD + (size_t)g * kH + c] = a;   // z_pool
    zp[c] = a;
    __syncthreads();
    float t = bd1[c];
    #pragma unroll 8
    for (int k = 0; k < kH; ++k) t = fmaf(zp[k], Wd1[k * 64 + c], t);
    tt[c] = fmaxf(t, 0.f);
    __syncthreads();
    #pragma unroll
    for (int j4 = 0; j4 < 4; ++j4) {
        int col = c + j4 * 64;
        float v = bd2[col];
        #pragma unroll 8
        for (int k = 0; k < 64; ++k) v = fmaf(tt[k], Wd2[k * kD + col], v);
        out[(size_t)g * kD + col] = v;               // x_hat
    }
}

extern "C" void kernel_launch(void* const* d_in, const int* in_sizes, int n_in,
                              void* d_out, int out_size, void* d_ws, size_t ws_size,
                              hipStream_t stream) {
    const float* x    = (const float*)d_in[0];
    const int*   ei   = (const int*)d_in[1];
    const int*   src  = ei;
    const int*   dst  = ei + kE;
    const int*   batch= (const int*)d_in[2];
    const float* W1   = (const float*)d_in[3];
    const float* b1   = (const float*)d_in[4];
    const float* W2   = (const float*)d_in[5];
    const float* b2   = (const float*)d_in[6];
    const float* Wd1  = (const float*)d_in[7];
    const float* bd1  = (const float*)d_in[8];
    const float* Wd2  = (const float*)d_in[9];
    const float* bd2  = (const float*)d_in[10];
    float* out = (float*)d_out;

    char* ws = (char*)d_ws;
    int*     cnt_p  = (int*)(ws + OFF_CNTP);
    int*     gcnt   = (int*)(ws + OFF_GCNT);
    float*   q_raw  = (float*)(ws + OFF_QRAW);
    float*   dinv   = (float*)(ws + OFF_DINV);
    int*     cnt_c  = (int*)(ws + OFF_CNTC);
    int*     rowp_d = (int*)(ws + OFF_ROWPD);
    int*     bsum   = (int*)(ws + OFF_BSUM);
    int*     boff   = (int*)(ws + OFF_BOFF);
    int*     slot   = (int*)(ws + OFF_SLOT);
    int*     rec_d  = (int*)(ws + OFF_RECD);
    __half*  hl     = (__half*)(ws + OFF_HL);
    __half*  h      = (__half*)(ws + OFF_H2);

    hipMemsetAsync(d_ws, 0, ZERO_BYTES, stream);

    const int nScanBlocks = (kN + 255) / 256;  // 391

    k_hist<<<(kE + 255) / 256, 256, 0, stream>>>(dst, cnt_p, slot);
    k_gcnt<<<128, 256, 0, stream>>>(batch, gcnt);
    k_dinv<<<nScanBlocks, 256, 0, stream>>>(cnt_p, cnt_c, dinv, hl, h);

    k_scan1<<<nScanBlocks, 256, 0, stream>>>(cnt_c, rowp_d, bsum);
    k_scan2<<<1, 512, 0, stream>>>(bsum, boff, nScanBlocks);
    k_scan3<<<nScanBlocks, 256, 0, stream>>>(rowp_d, boff);

    k_fill<<<(kE + 255) / 256, 256, 0, stream>>>(src, dst, slot, rowp_d, rec_d);

    k_gemm1<<<(kN + 63) / 64, 256, 0, stream>>>(x, W1, dinv, hl);

    k_conv1<<<(kN + 3) / 4, 256, 0, stream>>>(rec_d, rowp_d, cnt_c, dinv, hl, b1, h);

    k_pool3<<<(kN / 8 + 3) / 4, 256, 0, stream>>>(rec_d, rowp_d, cnt_c, dinv, h, batch, q_raw);

    k_head<<<kG, 64, 0, stream>>>(q_raw, gcnt, W2, b2, Wd1, bd1, Wd2, bd2, out);
}